// Round 11
// baseline (2050.903 us; speedup 1.0000x reference)
//
#include <hip/hip_runtime.h>
#include <cstdint>

typedef __attribute__((ext_vector_type(8))) short short8;
typedef __attribute__((ext_vector_type(4))) float f32x4;
typedef __attribute__((ext_vector_type(2))) float f32x2;

#define TPB  256
#define MB   32      // batch rows per block (two 16-row groups per wave)
#define HS   50      // hidden size
#define HSTR 72      // h row stride in halves (144B, 16B-aligned)
#define XSTR 68      // x row stride in u32 (272B, 16B-aligned)
#define L2E  1.4426950408889634f
#define L2E2 2.8853900817779268f

__device__ __forceinline__ float ex2(float x) {
#if __has_builtin(__builtin_amdgcn_exp2f)
  return __builtin_amdgcn_exp2f(x);
#else
  float r; asm("v_exp_f32 %0, %1" : "=v"(r) : "v"(x)); return r;
#endif
}
__device__ __forceinline__ float rcp_(float x) {
#if __has_builtin(__builtin_amdgcn_rcpf)
  return __builtin_amdgcn_rcpf(x);
#else
  float r; asm("v_rcp_f32 %0, %1" : "=v"(r) : "v"(x)); return r;
#endif
}
__device__ __forceinline__ unsigned short bf16_rne(float f) {
  unsigned r;
  asm("v_cvt_pk_bf16_f32 %0, %1, %2" : "=v"(r) : "v"(f), "v"(f));
  return (unsigned short)r;
}
__device__ __forceinline__ unsigned cvtpk2(float a, float b) {
  unsigned r;
  asm("v_cvt_pk_bf16_f32 %0, %1, %2" : "=v"(r) : "v"(a), "v"(b));
  return r;   // lo = a, hi = b
}
__device__ __forceinline__ float bf16f(unsigned short h) {
  union { unsigned u; float f; } v; v.u = ((unsigned)h) << 16; return v.f;
}
__device__ __forceinline__ unsigned packx(float f) {
  unsigned short hi = bf16_rne(f);
  unsigned short lo = bf16_rne(f - bf16f(hi));
  return (unsigned)hi | ((unsigned)lo << 16);
}
// column swizzle (identical helper on every read and write)
__device__ __forceinline__ int swcol(int row, int col) {
  return (((col >> 3) ^ ((row >> 2) & 3)) << 3) | (col & 7);
}

// Transposed GEMM per step, now 2 batch-groups per wave:
//   gates^T[256 n][32 b] = W[256 n][64 k] * hT[64 k][32 b]
//   A-operand = W fragments (static, registers), shared by both groups.
//   B-operands: group0 = h rows 0..15 (lane col l15), group1 = rows 16..31.
//   k 0..49 = h(t-1); reg-injected on b1: k50=xv_hi k51=xv_lo k52=xv_hi
//   k53=1 k54=1 (W frag1 slots: w_ih_hi, w_ih_hi, w_ih_lo, bias_hi, bias_lo).
//   Gate-chunk rotation g=(wid+rho)&3 balances the light chunk across SIMDs;
//   rho differs between co-resident blocks (n vs n+256).
//   Two independent MFMA->ELEM streams per wave = in-wave 2-deep ILP; one
//   barrier per step now covers 32 batches.
__global__ __launch_bounds__(TPB, 2)
void lstm_mfma11(const float* __restrict__ x,
                 const float* __restrict__ w_ih,
                 const float* __restrict__ w_hh,
                 const float* __restrict__ b_ih,
                 const float* __restrict__ b_hh,
                 const float* __restrict__ w_fc,
                 const float* __restrict__ b_fc,
                 float* __restrict__ out, int T)
{
  __shared__ __attribute__((aligned(16))) unsigned short hbuf[2][MB][HSTR];
  __shared__ __attribute__((aligned(16))) unsigned x_lds[2][MB][XSTR];

  const int tid  = threadIdx.x;
  const int wid  = tid >> 6;
  const int lane = tid & 63;
  const int l15  = lane & 15;
  const int lhi  = lane >> 4;      // 0..3
  const int b0   = blockIdx.x * MB;
  const int rho  = (blockIdx.x + (blockIdx.x >> 8)) & 3;
  const int g    = (wid + rho) & 3;   // j-chunk this wave owns
  const int j    = g * 16 + l15;      // W row this lane loads
  const bool jval  = (j < HS);
  const bool light = (g == 3);        // j=48..63: r=2,3 all-pad
  const bool inj   = (lhi == 2);      // b1 lanes carrying k=48..55

  // ---- build static W-fragments (A-operand), hi-only + xv/bias slots ----
  short8 Wh[4][2];
  #pragma unroll
  for (int s = 0; s < 4; ++s) {
    const float sc = (s == 2) ? L2E2 : L2E;
    float wsc = 0.f, bsc = 0.f;
    if (jval) {
      int row = s * HS + j;
      wsc = w_ih[row] * sc;
      bsc = (b_ih[row] + b_hh[row]) * sc;
    }
    const unsigned short wh = bf16_rne(wsc);
    const unsigned short wl = bf16_rne(wsc - bf16f(wh));
    const unsigned short bh = bf16_rne(bsc);
    const unsigned short bl = bf16_rne(bsc - bf16f(bh));
    #pragma unroll
    for (int i = 0; i < 8; ++i) {           // frag 0: k = 0..31
      int k = lhi * 8 + i;
      Wh[s][0][i] = (short)(jval ? bf16_rne(w_hh[(s * HS + j) * HS + k] * sc) : 0);
    }
    #pragma unroll
    for (int i = 0; i < 8; ++i) {           // frag 1: k = 32..63
      int k = 32 + lhi * 8 + i;
      unsigned short hv = 0;
      if (jval) {
        if (k < HS)                  hv = bf16_rne(w_hh[(s * HS + j) * HS + k] * sc);
        else if (k == 50 || k == 51) hv = wh;
        else if (k == 52)            hv = wl;
        else if (k == 53)            hv = bh;
        else if (k == 54)            hv = bl;
      }
      Wh[s][1][i] = (short)hv;
    }
  }

  // ---- init LDS ----
  for (int idx = tid; idx < 2 * MB * HSTR; idx += TPB)
    (&hbuf[0][0][0])[idx] = 0;
  {
    // stage x chunk 0: row = batch (tid>>3), cols (tid&7)*8 .. +7
    int bb = tid >> 3, base = (tid & 7) * 8;
    const float* xr = x + (size_t)(b0 + bb) * T + base;
    const f32x4 v0 = *(const f32x4*)(xr);
    const f32x4 v1 = *(const f32x4*)(xr + 4);
    uint4 u0, u1;
    u0.x = packx(v0[0]); u0.y = packx(v0[1]); u0.z = packx(v0[2]); u0.w = packx(v0[3]);
    u1.x = packx(v1[0]); u1.y = packx(v1[1]); u1.z = packx(v1[2]); u1.w = packx(v1[3]);
    *(uint4*)&x_lds[0][bb][base]     = u0;
    *(uint4*)&x_lds[0][bb][base + 4] = u1;
  }
  __syncthreads();

  // loop-invariant LDS offsets (halves); keyr invariant under row+16
  const int keyr  = (l15 >> 2) & 3;
  const int offA0 = l15 * HSTR + ((lhi ^ keyr) << 3);
  const int offA1 = l15 * HSTR + (((lhi + 4) ^ keyr) << 3);
  const int offW  = l15 * HSTR + ((((g * 2 + (lhi >> 1)) ^ keyr) << 3)) + (lhi & 1) * 4;
  const int GRP   = 16 * HSTR;   // +16 rows for batch-group 1

  // cell states (scaled c~ = 2*log2e*c): group0 rows r0,1|r2,3; group1 same
  f32x2 cA0 = {0.f, 0.f}, cB0 = {0.f, 0.f};
  f32x2 cA1 = {0.f, 0.f}, cB1 = {0.f, 0.f};
  f32x4 xf0 = {0.f, 0.f, 0.f, 0.f}, xf1 = {0.f, 0.f, 0.f, 0.f};
  const int nch = T >> 6;   // T multiple of 64 (T=2048)

  // elementwise core (identical arithmetic to round-7/10 known-good)
  auto ELEM = [&](f32x2 ai, f32x2 af, f32x2 ag, f32x2 ao, f32x2& c2) -> f32x2 {
    f32x2 u, v, w, z, q, rD, r3, vm1;
    u[0] = ex2(-ai[0]); u[1] = ex2(-ai[1]);
    v[0] = ex2( ag[0]); v[1] = ex2( ag[1]);
    w[0] = ex2(-af[0]); w[1] = ex2(-af[1]);
    z[0] = ex2(-ao[0]); z[1] = ex2(-ao[1]);
    f32x2 t1 = (u + 1.f) * (v + 1.f);
    f32x2 wp = w + 1.f;
    f32x2 D  = t1 * wp;
    rD[0] = rcp_(D[0]); rD[1] = rcp_(D[1]);
    vm1[0] = fmaf(v[0], L2E2, -L2E2);
    vm1[1] = fmaf(v[1], L2E2, -L2E2);
    f32x2 num = c2 * t1 + vm1 * wp;
    f32x2 cn = num * rD;
    cn[0] = fminf(fmaxf(cn[0], -86.f), 86.f);
    cn[1] = fminf(fmaxf(cn[1], -86.f), 86.f);
    c2 = cn;
    q[0] = ex2(cn[0]); q[1] = ex2(cn[1]);
    f32x2 t3 = (z + 1.f) * (q + 1.f);
    r3[0] = rcp_(t3[0]); r3[1] = rcp_(t3[1]);
    return (q - 1.f) * r3;
  };

  auto STEP = [&](const unsigned short* hr, unsigned short* hw,
                  const unsigned* xrowA, const unsigned* xrowB, int slot) {
    const unsigned xpa = xrowA[slot];
    const unsigned xpb = xrowB[slot];

    // group 0 B-frags (+ xv/bias injection on lhi==2 lanes)
    const short8 B0a = *(const short8*)(hr + offA0);
    union { short8 s8; unsigned u[4]; } b1a, b1b;
    b1a.s8 = *(const short8*)(hr + offA1);
    b1a.u[1] = inj ? xpa : b1a.u[1];
    b1a.u[2] = inj ? ((xpa & 0xFFFFu) | 0x3F800000u) : b1a.u[2];
    b1a.u[3] = inj ? 0x00003F80u : b1a.u[3];
    // group 1
    const short8 B0b = *(const short8*)(hr + offA0 + GRP);
    b1b.s8 = *(const short8*)(hr + offA1 + GRP);
    b1b.u[1] = inj ? xpb : b1b.u[1];
    b1b.u[2] = inj ? ((xpb & 0xFFFFu) | 0x3F800000u) : b1b.u[2];
    b1b.u[3] = inj ? 0x00003F80u : b1b.u[3];

    __builtin_amdgcn_s_setprio(1);
    f32x4 acc0[4], acc1[4];
    #pragma unroll
    for (int s = 0; s < 4; ++s) {
      acc0[s] = __builtin_amdgcn_mfma_f32_16x16x32_bf16(Wh[s][0], B0a,
                    (f32x4){0.f, 0.f, 0.f, 0.f}, 0, 0, 0);
      acc1[s] = __builtin_amdgcn_mfma_f32_16x16x32_bf16(Wh[s][0], B0b,
                    (f32x4){0.f, 0.f, 0.f, 0.f}, 0, 0, 0);
      acc0[s] = __builtin_amdgcn_mfma_f32_16x16x32_bf16(Wh[s][1], b1a.s8, acc0[s], 0, 0, 0);
      acc1[s] = __builtin_amdgcn_mfma_f32_16x16x32_bf16(Wh[s][1], b1b.s8, acc1[s], 0, 0, 0);
    }
    __builtin_amdgcn_s_setprio(0);

    // group 0 elementwise + write (rows l15)
    {
      f32x2 h2A = ELEM((f32x2){acc0[0][0], acc0[0][1]}, (f32x2){acc0[1][0], acc0[1][1]},
                       (f32x2){acc0[2][0], acc0[2][1]}, (f32x2){acc0[3][0], acc0[3][1]}, cA0);
      unsigned hx = cvtpk2(h2A[0], h2A[1]);
      if (!light) {
        f32x2 h2B = ELEM((f32x2){acc0[0][2], acc0[0][3]}, (f32x2){acc0[1][2], acc0[1][3]},
                         (f32x2){acc0[2][2], acc0[2][3]}, (f32x2){acc0[3][2], acc0[3][3]}, cB0);
        uint2 hwv; hwv.x = hx; hwv.y = cvtpk2(h2B[0], h2B[1]);
        *(uint2*)(hw + offW) = hwv;
      } else {
        *(unsigned*)(hw + offW) = hx;
      }
    }
    // group 1 elementwise + write (rows l15+16)
    {
      f32x2 h2A = ELEM((f32x2){acc1[0][0], acc1[0][1]}, (f32x2){acc1[1][0], acc1[1][1]},
                       (f32x2){acc1[2][0], acc1[2][1]}, (f32x2){acc1[3][0], acc1[3][1]}, cA1);
      unsigned hx = cvtpk2(h2A[0], h2A[1]);
      if (!light) {
        f32x2 h2B = ELEM((f32x2){acc1[0][2], acc1[0][3]}, (f32x2){acc1[1][2], acc1[1][3]},
                         (f32x2){acc1[2][2], acc1[2][3]}, (f32x2){acc1[3][2], acc1[3][3]}, cB1);
        uint2 hwv; hwv.x = hx; hwv.y = cvtpk2(h2B[0], h2B[1]);
        *(uint2*)(hw + offW + GRP) = hwv;
      } else {
        *(unsigned*)(hw + offW + GRP) = hx;
      }
    }

    __syncthreads();
  };

  unsigned short* hb0 = &hbuf[0][0][0];
  unsigned short* hb1 = &hbuf[1][0][0];

  for (int ch = 0; ch < nch; ++ch) {
    const int par = ch & 1;
    const unsigned* xrowA = &x_lds[par][l15][0];
    const unsigned* xrowB = &x_lds[par][l15 + 16][0];
    int slot = 0;
    #pragma unroll 1
    for (int i = 0; i < 8; ++i) {          // slots 0..15
      STEP(hb0, hb1, xrowA, xrowB, slot);
      STEP(hb1, hb0, xrowA, xrowB, slot + 1); slot += 2;
    }
    if (ch + 1 < nch) {                    // issue next-chunk global load (~slot 16)
      const float* xr = x + (size_t)(b0 + (tid >> 3)) * T + (ch + 1) * 64 + (tid & 7) * 8;
      xf0 = *(const f32x4*)(xr);
      xf1 = *(const f32x4*)(xr + 4);
    }
    #pragma unroll 1
    for (int i = 0; i < 14; ++i) {         // slots 16..43
      STEP(hb0, hb1, xrowA, xrowB, slot);
      STEP(hb1, hb0, xrowA, xrowB, slot + 1); slot += 2;
    }
    if (ch + 1 < nch) {                    // write next-chunk x to LDS (~slot 44)
      uint4 u0, u1;
      u0.x = packx(xf0[0]); u0.y = packx(xf0[1]); u0.z = packx(xf0[2]); u0.w = packx(xf0[3]);
      u1.x = packx(xf1[0]); u1.y = packx(xf1[1]); u1.z = packx(xf1[2]); u1.w = packx(xf1[3]);
      int bb = tid >> 3, base = (tid & 7) * 8;
      *(uint4*)&x_lds[par ^ 1][bb][base]     = u0;
      *(uint4*)&x_lds[par ^ 1][bb][base + 4] = u1;
    }
    #pragma unroll 1
    for (int i = 0; i < 10; ++i) {         // slots 44..63
      STEP(hb0, hb1, xrowA, xrowB, slot);
      STEP(hb1, hb0, xrowA, xrowB, slot + 1); slot += 2;
    }
  }

  // fc head on final h (T even -> final h in hbuf[0])
  if (tid < MB) {
    const unsigned short* hfin = hb0 + tid * HSTR;
    float s = 0.f;
    for (int jj = 0; jj < HS; ++jj)
      s = fmaf(bf16f(hfin[swcol(tid, jj)]), w_fc[jj], s);
    out[b0 + tid] = s + b_fc[0];
  }
}

extern "C" void kernel_launch(void* const* d_in, const int* in_sizes, int n_in,
                              void* d_out, int out_size, void* d_ws, size_t ws_size,
                              hipStream_t stream) {
  const float* x    = (const float*)d_in[0];
  const float* w_ih = (const float*)d_in[1];
  const float* w_hh = (const float*)d_in[2];
  const float* b_ih = (const float*)d_in[3];
  const float* b_hh = (const float*)d_in[4];
  const float* w_fc = (const float*)d_in[5];
  const float* b_fc = (const float*)d_in[6];
  float* out = (float*)d_out;

  const int B = out_size;          // 16384
  const int T = in_sizes[0] / B;   // 2048

  dim3 grid(B / MB), block(TPB);
  hipLaunchKernelGGL(lstm_mfma11, grid, block, 0, stream,
                     x, w_ih, w_hh, b_ih, b_hh, w_fc, b_fc, out, T);
}